// Round 15
// baseline (209.352 us; speedup 1.0000x reference)
//
#include <hip/hip_runtime.h>
#include <hip/hip_bf16.h>
#include <math.h>

#define B_   16
#define INP  32
#define OUP  64
#define HID  192
#define H_   96
#define W_   96
#define HW_  (H_*W_)   // 9216
#define TC   48
#define TR   48

typedef __attribute__((ext_vector_type(8))) short  bf16x8;
typedef __attribute__((ext_vector_type(4))) float  f32x4;

__device__ __forceinline__ float relu6f(float v) { return fminf(fmaxf(v, 0.f), 6.f); }
__device__ __forceinline__ float bf2f(unsigned short u) {
    unsigned int x = ((unsigned int)u) << 16;
    return __uint_as_float(x);
}
__device__ __forceinline__ unsigned short f2bf(float f) {
    unsigned int x = __float_as_uint(f);
    unsigned int lsb = (x >> 16) & 1u;
    x += 0x7fffu + lsb;
    return (unsigned short)(x >> 16);
}

// ---------------------------------------------------------------------------
// K0: prep — BN1-folded bf16 w1b + t1; BN3-folded w2t + t3; BN2 -> sc2/sh2;
// zero se_part.
// ---------------------------------------------------------------------------
__global__ __launch_bounds__(256) void k0_prep(
    const float* __restrict__ w1, const float* __restrict__ g1,
    const float* __restrict__ b1, const float* __restrict__ m1,
    const float* __restrict__ v1,
    const float* __restrict__ w2, const float* __restrict__ g3,
    const float* __restrict__ b3, const float* __restrict__ m3,
    const float* __restrict__ v3,
    const float* __restrict__ g2, const float* __restrict__ b2,
    const float* __restrict__ m2, const float* __restrict__ v2,
    unsigned short* __restrict__ w1b, float* __restrict__ t1,
    float* __restrict__ w2t, float* __restrict__ t3,
    float* __restrict__ se_part, float* __restrict__ sc2,
    float* __restrict__ sh2)
{
    const int idx = blockIdx.x*256 + threadIdx.x;
    if (idx < HID*INP) {                                    // w1b (bf16)
        int o = idx / INP;
        w1b[idx] = f2bf(w1[idx] * g1[o]*rsqrtf(v1[o] + 1e-5f));
    } else if (idx < HID*INP + HID) {                       // t1
        int o = idx - HID*INP;
        float sc = g1[o]*rsqrtf(v1[o] + 1e-5f);
        t1[o] = b1[o] - m1[o]*sc;
    } else if (idx < HID*INP + HID + HID*OUP) {             // w2t
        int k = idx - (HID*INP + HID);
        int c = k / OUP, o = k % OUP;
        w2t[k] = w2[o*HID + c] * g3[o]*rsqrtf(v3[o] + 1e-5f);
    } else if (idx < HID*INP + HID + HID*OUP + OUP) {       // t3
        int o = idx - (HID*INP + HID + HID*OUP);
        float sc = g3[o]*rsqrtf(v3[o] + 1e-5f);
        t3[o] = b3[o] - m3[o]*sc;
    } else if (idx < HID*INP + HID + HID*OUP + OUP + B_*36) { // zero se_part
        se_part[idx - (HID*INP + HID + HID*OUP + OUP)] = 0.f;
    } else if (idx < HID*INP + HID + HID*OUP + OUP + B_*36 + HID) { // sc2
        int c = idx - (HID*INP + HID + HID*OUP + OUP + B_*36);
        sc2[c] = g2[c]*rsqrtf(v2[c] + 1e-5f);
    } else if (idx < HID*INP + HID + HID*OUP + OUP + B_*36 + 2*HID) { // sh2
        int c = idx - (HID*INP + HID + HID*OUP + OUP + B_*36 + HID);
        float sc = g2[c]*rsqrtf(v2[c] + 1e-5f);
        sh2[c] = b2[c] - m2[c]*sc;
    }
}

// ---------------------------------------------------------------------------
// K1 (MFMA): 1x1 conv (32->192) + BN1 + ReLU6 -> y (bf16); SE-weighted pool.
// ---------------------------------------------------------------------------
__global__ __launch_bounds__(256) void k1_mfma(
    const float* __restrict__ x, const unsigned short* __restrict__ w1b,
    const float* __restrict__ t1, const float* __restrict__ se_w,
    unsigned short* __restrict__ y, float* __restrict__ se_part)
{
    __shared__ unsigned short wl[HID*INP];   // 12 KiB  [oc][k] bf16
    __shared__ unsigned short xT[64*INP];    //  4 KiB  [px][k] bf16
    __shared__ float t1l[HID], sewl[HID];
    const int tid = threadIdx.x;
    const int bid = blockIdx.x;              // b*144 + strip64
    const int b   = bid / 144;
    const int inpx0 = (bid % 144) * 64;

    {
        const uint4* src = (const uint4*)w1b;
        uint4* dst = (uint4*)wl;
        dst[tid] = src[tid];
        if (tid < 256) { dst[tid+256] = src[tid+256]; dst[tid+512] = src[tid+512]; }
    }
    if (tid < HID) { t1l[tid] = t1[tid]; sewl[tid] = se_w[tid]; }
    {
        const int ch = tid >> 3, q8 = tid & 7;
        const float* xp = x + (size_t)(b*INP + ch)*HW_ + inpx0 + q8*8;
        float4 v0 = *(const float4*)(xp);
        float4 v1 = *(const float4*)(xp + 4);
        int p0 = q8*8;
        xT[(p0+0)*INP + ch] = f2bf(v0.x);
        xT[(p0+1)*INP + ch] = f2bf(v0.y);
        xT[(p0+2)*INP + ch] = f2bf(v0.z);
        xT[(p0+3)*INP + ch] = f2bf(v0.w);
        xT[(p0+4)*INP + ch] = f2bf(v1.x);
        xT[(p0+5)*INP + ch] = f2bf(v1.y);
        xT[(p0+6)*INP + ch] = f2bf(v1.z);
        xT[(p0+7)*INP + ch] = f2bf(v1.w);
    }
    __syncthreads();

    const int w = tid >> 6;
    const int l = tid & 63;
    const int pxl = l & 15;
    const int kb  = l >> 4;

    const bf16x8 bfrag = *(const bf16x8*)&xT[(w*16 + pxl)*INP + kb*8];
    const size_t ybase = (size_t)b*HID*HW_ + inpx0 + w*16 + pxl;
    float psum = 0.f;

    #pragma unroll
    for (int T = 0; T < 12; ++T) {
        const bf16x8 afrag = *(const bf16x8*)&wl[(T*16 + pxl)*INP + kb*8];
        f32x4 acc = __builtin_amdgcn_mfma_f32_16x16x32_bf16(
                        afrag, bfrag, (f32x4){0.f,0.f,0.f,0.f}, 0, 0, 0);
        const int oc0 = T*16 + kb*4;
        const float4 t1v = *(const float4*)&t1l[oc0];
        const float4 swv = *(const float4*)&sewl[oc0];
        float yv0 = relu6f(acc[0] + t1v.x);
        float yv1 = relu6f(acc[1] + t1v.y);
        float yv2 = relu6f(acc[2] + t1v.z);
        float yv3 = relu6f(acc[3] + t1v.w);
        psum += swv.x*yv0 + swv.y*yv1 + swv.z*yv2 + swv.w*yv3;
        y[ybase + (size_t)(oc0+0)*HW_] = f2bf(yv0);
        y[ybase + (size_t)(oc0+1)*HW_] = f2bf(yv1);
        y[ybase + (size_t)(oc0+2)*HW_] = f2bf(yv2);
        y[ybase + (size_t)(oc0+3)*HW_] = f2bf(yv3);
    }

    #pragma unroll
    for (int off = 32; off > 0; off >>= 1) psum += __shfl_down(psum, off, 64);
    if (l == 0) {
        const int spx = inpx0 + w*16;
        const int h = spx / W_, w0 = spx % W_;
        const int cell = (h >> 4)*6 + (w0 >> 4);
        atomicAdd(&se_part[b*36 + cell], psum);
    }
}

// ---------------------------------------------------------------------------
// K3: per (b,h) row — sigmoid(se_part) in-block, SE upsample, cumsum,
// searchsorted -> iABW={i,A,B,_}, mm  (k2 folded in)
// ---------------------------------------------------------------------------
__global__ __launch_bounds__(128) void k3_rows(
    const float* __restrict__ se_part, const float* __restrict__ se_b,
    float4* __restrict__ iABW, float* __restrict__ mm)
{
    const int bx = blockIdx.x;            // b*H_ + h
    const int b = bx / H_, h = bx % H_;
    const int tid = threadIdx.x;
    __shared__ float s6l[36];
    __shared__ float ysr[W_];
    __shared__ float xxl[W_];

    if (tid < 36) {
        float logit = se_part[b*36 + tid]*(1.f/256.f) + se_b[0];
        s6l[tid] = 1.f/(1.f + expf(-logit));
    }
    __syncthreads();

    float ch = h * (5.0f/95.0f);
    int r0 = (int)floorf(ch); r0 = min(max(r0, 0), 4);
    float fr = ch - (float)r0;

    if (tid < W_) {
        float cw = tid * (5.0f/95.0f);
        int c0 = (int)floorf(cw); c0 = min(max(c0, 0), 4);
        float fc = cw - (float)c0;
        float v00 = s6l[r0*6 + c0],     v01 = s6l[r0*6 + c0 + 1];
        float v10 = s6l[(r0+1)*6 + c0], v11 = s6l[(r0+1)*6 + c0 + 1];
        float ra = v00*(1.f-fr) + v10*fr;
        float rb = v01*(1.f-fr) + v11*fr;
        ysr[tid] = ra*(1.f-fc) + rb*fc;
    }
    __syncthreads();
    if (tid == 0) {
        float rs = 0.f;
        for (int w = 0; w < W_; ++w) rs += ysr[w] + 0.001f;
        float scale = (W_*0.5f)/rs;
        float cum = 0.f;
        for (int w = 0; w < W_; ++w) { cum += scale*(ysr[w]+0.001f) + 0.5f; xxl[w] = cum; }
    }
    __syncthreads();
    if (tid < TC) {
        float cq = tid * 2.0f;
        int cnt = 0;
        for (int w = 0; w < W_; ++w) cnt += (xxl[w] < cq) ? 1 : 0;
        int i = min(max(cnt - 1, 0), W_ - 2);
        float x0 = xxl[i], x1 = xxl[i+1];
        float t = (cq - x0)/(x1 - x0);
        int idx = bx*TC + tid;
        float s0 = ysr[i], s1v = ysr[i+1];
        iABW[idx] = make_float4((float)i, s0*(1.f - t), s1v*t, 0.f);
        mm[idx] = s0 + (s1v - s0)*t;
    }
}

// ---------------------------------------------------------------------------
// K5: per (b,j) column — cumsum over h, searchsorted -> i2AB={i2,A2,B2,_}[b][r][j]
// ---------------------------------------------------------------------------
__global__ __launch_bounds__(128) void k5_cols(
    const float* __restrict__ mm, float4* __restrict__ i2AB)
{
    const int bx = blockIdx.x;            // b*TC + j
    const int b = bx / TC, j = bx % TC;
    const int tid = threadIdx.x;
    __shared__ float cmv[H_], yyl[H_];

    if (tid < H_) cmv[tid] = mm[(b*H_ + tid)*TC + j] + 0.001f;
    __syncthreads();
    if (tid == 0) {
        float cs = 0.f;
        for (int hh = 0; hh < H_; ++hh) cs += cmv[hh];
        float scale = (H_*0.5f)/cs;
        float cum = 0.f;
        for (int hh = 0; hh < H_; ++hh) { cum += scale*cmv[hh] + 0.5f; yyl[hh] = cum; }
    }
    __syncthreads();
    if (tid < TR) {
        float rq = tid * 2.0f;
        int cnt = 0;
        for (int hh = 0; hh < H_; ++hh) cnt += (yyl[hh] < rq) ? 1 : 0;
        int i2 = min(max(cnt - 1, 0), H_ - 2);
        float p0 = yyl[i2], p1 = yyl[i2+1];
        float t2 = (rq - p0)/(p1 - p0);
        int idx = (b*TR + tid)*TC + j;
        i2AB[idx] = make_float4((float)i2, 1.f - t2, t2, 0.f);
    }
}

// ---------------------------------------------------------------------------
// K4: FUSED horizontal warp + vertical warp + depthwise 3x3 + BN2 + ReLU6.
// block = one (b,c) plane; mf (18K) + ff (9K) in LDS; y gathered via L1/L2.
// ---------------------------------------------------------------------------
__global__ __launch_bounds__(256) void k4_warp_dw(
    const unsigned short* __restrict__ y,
    const float4* __restrict__ iABW,
    const float4* __restrict__ i2AB,
    const float* __restrict__ wdw,
    const float* __restrict__ sc2, const float* __restrict__ sh2,
    float* __restrict__ z1)
{
    __shared__ float mfs[H_*TC];         // 18 KiB
    __shared__ float ffs[TR*TC];         //  9 KiB
    const int tid = threadIdx.x;
    const int b = blockIdx.x / HID;
    const int c = blockIdx.x % HID;
    const unsigned short* yp = y + (size_t)(b*HID + c)*HW_;

    const int rbase = b*H_*TC;
    #pragma unroll
    for (int t = 0; t < (H_*TC)/256; ++t) {
        int k = tid + t*256;
        int h = k / TC;
        float4 f = iABW[rbase + k];
        int i = (int)f.x;
        float y0 = bf2f(yp[h*W_ + i]);
        float y1 = bf2f(yp[h*W_ + i + 1]);
        mfs[k] = y0*f.y + y1*f.z;
    }
    __syncthreads();

    const int r2base = b*TR*TC;
    #pragma unroll
    for (int t = 0; t < (TR*TC)/256; ++t) {
        int k = tid + t*256;
        int j = k % TC;
        float4 f = i2AB[r2base + k];
        int i2 = (int)f.x;
        ffs[k] = mfs[i2*TC + j]*f.y + mfs[(i2+1)*TC + j]*f.z;
    }

    float wk[9];
    #pragma unroll
    for (int k = 0; k < 9; ++k) wk[k] = wdw[c*9 + k];
    const float sc = sc2[c], sh = sh2[c];
    __syncthreads();

    float* zp = z1 + (size_t)(b*HID + c)*TR*TC;
    #pragma unroll
    for (int t = 0; t < (TR*TC)/256; ++t) {
        int k = tid + t*256;
        int r = k / TC, j = k % TC;
        float acc = 0.f;
        #pragma unroll
        for (int dr = -1; dr <= 1; ++dr)
            #pragma unroll
            for (int dj = -1; dj <= 1; ++dj) {
                int rr = r + dr, jj = j + dj;
                if (rr >= 0 && rr < TR && jj >= 0 && jj < TC)
                    acc += ffs[rr*TC + jj]*wk[(dr+1)*3 + (dj+1)];
            }
        zp[k] = relu6f(acc*sc + sh);
    }
}

// ---------------------------------------------------------------------------
// K8: 1x1 conv (192->64) + BN3 -> out. Register-tiled, 32 px/block:
// thread = 4 px (float4) x 2 outputs; block = 8 pxg x 32 o-chunks;
// grid 1152 (-> ~18 waves/CU, was 9).
// ---------------------------------------------------------------------------
__global__ __launch_bounds__(256) void k8_conv2(
    const float* __restrict__ z1, const float* __restrict__ w2t,
    const float* __restrict__ t3, float* __restrict__ out)
{
    const int tid = threadIdx.x;
    const int pxg = tid & 7;                 // 8 pixel-groups of 4
    const int oc  = tid >> 3;                // 32 o-chunks of 2
    const int pix0 = blockIdx.x*32 + pxg*4;  // 32 divides 2304 -> b uniform
    const int b   = pix0 / (TR*TC);
    const int sp  = pix0 % (TR*TC);

    float acc[4][2];
    #pragma unroll
    for (int p = 0; p < 4; ++p) { acc[p][0] = 0.f; acc[p][1] = 0.f; }

    const float* zb = z1 + (size_t)b*HID*TR*TC + sp;
    const float* wb = w2t + oc*2;
    #pragma unroll 4
    for (int c = 0; c < HID; ++c) {
        float4 z = *(const float4*)(zb + (size_t)c*TR*TC);
        float2 w = *(const float2*)(wb + c*OUP);
        acc[0][0] += z.x*w.x; acc[0][1] += z.x*w.y;
        acc[1][0] += z.y*w.x; acc[1][1] += z.y*w.y;
        acc[2][0] += z.z*w.x; acc[2][1] += z.z*w.y;
        acc[3][0] += z.w*w.x; acc[3][1] += z.w*w.y;
    }

    const float2 tt = *(const float2*)(t3 + oc*2);
    float* ob = out + (size_t)b*OUP*TR*TC + sp;
    #pragma unroll
    for (int o = 0; o < 2; ++o) {
        float tb = (o==0) ? tt.x : tt.y;
        float4 r = make_float4(acc[0][o]+tb, acc[1][o]+tb, acc[2][o]+tb, acc[3][o]+tb);
        *(float4*)(ob + (size_t)(oc*2 + o)*TR*TC) = r;
    }
}

// ---------------------------------------------------------------------------
extern "C" void kernel_launch(void* const* d_in, const int* in_sizes, int n_in,
                              void* d_out, int out_size, void* d_ws, size_t ws_size,
                              hipStream_t stream)
{
    const float* x    = (const float*)d_in[0];
    const float* w1   = (const float*)d_in[1];
    const float* g1   = (const float*)d_in[2];
    const float* b1   = (const float*)d_in[3];
    const float* m1   = (const float*)d_in[4];
    const float* v1   = (const float*)d_in[5];
    const float* se_w = (const float*)d_in[6];
    const float* se_b = (const float*)d_in[7];
    const float* wdw  = (const float*)d_in[8];
    const float* g2   = (const float*)d_in[9];
    const float* b2   = (const float*)d_in[10];
    const float* m2   = (const float*)d_in[11];
    const float* v2   = (const float*)d_in[12];
    const float* w2   = (const float*)d_in[13];
    const float* g3   = (const float*)d_in[14];
    const float* b3   = (const float*)d_in[15];
    const float* m3   = (const float*)d_in[16];
    const float* v3   = (const float*)d_in[17];
    float* out = (float*)d_out;

    float* ws = (float*)d_ws;
    unsigned short* y = (unsigned short*)ws;     // 28,311,552 bf16
    float*  z1     = ws + 14155776;              //  7,077,888
    float4* iABW   = (float4*)(ws + 21233664);   //     73,728 float4
    float*  mm     = ws + 21528576;              //     73,728
    float4* i2AB   = (float4*)(ws + 21602304);   //     36,864 float4
    float*  se_part= ws + 21749760;              //        576
    unsigned short* w1b = (unsigned short*)(ws + 21750336); // 6,144 bf16
    float*  t1     = ws + 21753408;              //        192
    float*  w2t    = ws + 21753600;              //     12,288
    float*  t3     = ws + 21765888;              //         64
    float*  sc2    = ws + 21765952;              //        192
    float*  sh2    = ws + 21766144;              //        192

    k0_prep<<<77, 256, 0, stream>>>(w1, g1, b1, m1, v1, w2, g3, b3, m3, v3,
                                    g2, b2, m2, v2,
                                    w1b, t1, w2t, t3, se_part, sc2, sh2);
    k1_mfma<<<B_*144, 256, 0, stream>>>(x, w1b, t1, se_w, y, se_part);
    k3_rows<<<B_*H_, 128, 0, stream>>>(se_part, se_b, iABW, mm);
    k5_cols<<<B_*TC, 128, 0, stream>>>(mm, i2AB);
    k4_warp_dw<<<B_*HID, 256, 0, stream>>>(y, iABW, i2AB, wdw, sc2, sh2, z1);
    k8_conv2<<<(B_*TR*TC)/32, 256, 0, stream>>>(z1, w2t, t3, out);
}